// Round 1
// baseline (522.132 us; speedup 1.0000x reference)
//
#include <hip/hip_runtime.h>

typedef __bf16 bf16x8 __attribute__((ext_vector_type(8)));
typedef __bf16 bf16x2 __attribute__((ext_vector_type(2)));
typedef float  f32x4  __attribute__((ext_vector_type(4)));
typedef int    i32x4  __attribute__((ext_vector_type(4)));

static constexpr int kS = 8192;
static constexpr int kD = 128;
static constexpr int kRowsPerTensor = 2 * 16 * kS;            // 262144
static constexpr int kFragElems = kD * kD;                    // 16384 bf16 per matrix

// ---------------------------------------------------------------------------
// Kernel 1: build Householder product Q, column-parallel (one wave per column).
// Emits:
//   wsQrm : Q row-major bf16 (A-operand of GEMM1; lane reads 16B rows directly)
//   wsQf  : Q in MFMA B-fragment order (B-operand of GEMM2)
// ---------------------------------------------------------------------------
__global__ __launch_bounds__(1024) void rnrope_build_q(
    const float* __restrict__ vs,
    __bf16* __restrict__ wsQrm,
    __bf16* __restrict__ wsQf) {
  __shared__ float vsh[64 * 128];
  const int tid = threadIdx.x;
  for (int i = tid; i < 2048; i += 1024)
    ((float4*)vsh)[i] = ((const float4*)vs)[i];
  __syncthreads();

  const int col  = blockIdx.x * 16 + (tid >> 6);  // 0..127 (grid = 8 blocks)
  const int lane = tid & 63;

  float qlo = (col == lane)      ? 1.0f : 0.0f;   // Q[lane][col]
  float qhi = (col == lane + 64) ? 1.0f : 0.0f;   // Q[lane+64][col]

  for (int r = 0; r < 64; ++r) {
    float vlo = vsh[r * 128 + lane];
    float vhi = vsh[r * 128 + lane + 64];
    float t0 = vlo * qlo + vhi * qhi;   // partial v . q_col
    float t1 = vlo * vlo + vhi * vhi;   // partial v . v
    #pragma unroll
    for (int off = 32; off > 0; off >>= 1) {
      t0 += __shfl_xor(t0, off);
      t1 += __shfl_xor(t1, off);
    }
    float sf = 2.0f / (t1 + 1e-8f) * t0;
    qlo -= sf * vlo;
    qhi -= sf * vhi;
  }

  // Q row-major (A-operand of GEMM1: A[e][d] = Q[e][d])
  wsQrm[lane * 128 + col]        = (__bf16)qlo;
  wsQrm[(lane + 64) * 128 + col] = (__bf16)qhi;

  // Q frag-ordered (B-operand of GEMM2: B[k][n] = Q[k][n])
  {
    const int nt = col >> 4;
    const int nn = col & 15;
    #pragma unroll
    for (int h = 0; h < 2; ++h) {
      int i = lane + h * 64;
      float val = h ? qhi : qlo;
      int ks = i >> 5, qd = (i >> 3) & 3, jj = i & 7;
      wsQf[((ks * 8 + nt) * 64 + qd * 16 + nn) * 8 + jj] = (__bf16)val;
    }
  }
}

// ---------------------------------------------------------------------------
// Kernel 2: barrier-free, LDS-free. One wave owns 32 rows (2 strips of 16).
// GEMM1 swapped: Yt = Q (A, from wsQrm) * X^T (B, straight from global f32).
// RoPE in-register on e-columns, pack to bf16, ds_bpermute crossbar to
// redistribute C-layout -> A-fragments, GEMM2: Z = Yr (A) * Q (B from wsQf),
// direct C-layout stores (4 x 64B segments per instr, merged in L2).
// Zero __syncthreads, zero LDS -> occupancy limited only by VGPRs.
// ---------------------------------------------------------------------------
__global__ __launch_bounds__(256, 3) void rnrope_main(
    const float* __restrict__ qg, const float* __restrict__ kg,
    const __bf16* __restrict__ wsQrm, const __bf16* __restrict__ wsQf,
    float* __restrict__ outg) {
  const int tid  = threadIdx.x;
  const int wv   = tid >> 6;     // wave 0..3
  const int lane = tid & 63;
  const int qd   = lane >> 4;    // quad
  const int cc   = lane & 15;

  const int blk    = blockIdx.x;          // 0..4095
  const int tensor = blk >> 11;           // 0 = q, 1 = k
  const int tile   = blk & 2047;
  const float* __restrict__ Xg = tensor ? kg : qg;
  float* __restrict__ Og = outg + (size_t)tensor * (size_t)kRowsPerTensor * kD;
  const int r0 = tile * 128 + wv * 32;    // this wave's 32 rows

  // --- X fragments (B-operand of GEMM1), both strips, straight from HBM -----
  // B[k][n]: lane needs X[r0 + s*16 + cc][ks*32 + qd*8 + j], j=0..7 contiguous.
  bf16x8 xb[2][4];
  #pragma unroll
  for (int s = 0; s < 2; ++s) {
    const float* rp = Xg + (size_t)(r0 + s * 16 + cc) * kD + qd * 8;
    #pragma unroll
    for (int ks = 0; ks < 4; ++ks) {
      float4 lo = *(const float4*)(rp + ks * 32);
      float4 hi = *(const float4*)(rp + ks * 32 + 4);
      bf16x8 v;
      v[0] = (__bf16)lo.x; v[1] = (__bf16)lo.y; v[2] = (__bf16)lo.z; v[3] = (__bf16)lo.w;
      v[4] = (__bf16)hi.x; v[5] = (__bf16)hi.y; v[6] = (__bf16)hi.z; v[7] = (__bf16)hi.w;
      xb[s][ks] = v;
    }
  }

  // --- GEMM1 (swapped): Yt[e][m] = sum_d Q[e][d] * X[m][d] ------------------
  // A-frag: lane holds Q[mt*16 + cc][ks*32 + qd*8 + j] -> 16B row-major loads
  // (L1/L2-resident 32KiB, reused by every wave on the CU).
  f32x4 acc[2][8];
  #pragma unroll
  for (int s = 0; s < 2; ++s)
    #pragma unroll
    for (int mt = 0; mt < 8; ++mt) acc[s][mt] = (f32x4){0.f, 0.f, 0.f, 0.f};

  #pragma unroll
  for (int mt = 0; mt < 8; ++mt) {
    #pragma unroll
    for (int ks = 0; ks < 4; ++ks) {
      bf16x8 a1 = *(const bf16x8*)(wsQrm + (mt * 16 + cc) * kD + ks * 32 + qd * 8);
      acc[0][mt] = __builtin_amdgcn_mfma_f32_16x16x32_bf16(a1, xb[0][ks], acc[0][mt], 0, 0, 0);
      acc[1][mt] = __builtin_amdgcn_mfma_f32_16x16x32_bf16(a1, xb[1][ks], acc[1][mt], 0, 0, 0);
    }
  }

  // --- RoPE in-register + pack + in-wave crossbar to A-fragments ------------
  // C layout (swapped): lane holds Yt[e = mt*16 + qd*4 + reg][m = cc].
  // Pair (e, e+64) = (acc[mt], acc[mt+4]) same reg; freq idx = e (< 64).
  const float kNegL = -0.20762050593046967f;   // -log2(10000)/64
  bf16x8 a2[2][4];
  #pragma unroll
  for (int s = 0; s < 2; ++s) {
    float spos = (float)((r0 + s * 16 + cc) & (kS - 1));
    #pragma unroll
    for (int mt = 0; mt < 4; ++mt) {
      #pragma unroll
      for (int reg = 0; reg < 4; ++reg) {
        float fe  = (float)(mt * 16 + qd * 4 + reg);
        float ang = spos * exp2f(kNegL * fe);
        float sv, cv;
        __sincosf(ang, &sv, &cv);
        float ylo = acc[s][mt][reg];
        float yhi = acc[s][mt + 4][reg];
        acc[s][mt][reg]     = ylo * cv - yhi * sv;   // e < 64
        acc[s][mt + 4][reg] = yhi * cv + ylo * sv;   // e >= 64
      }
    }
    // pack pairs (reg 2p, 2p+1) -> one dword of 2 x bf16
    int pw[16];
    #pragma unroll
    for (int mt = 0; mt < 8; ++mt) {
      #pragma unroll
      for (int p = 0; p < 2; ++p) {
        bf16x2 t;
        t[0] = (__bf16)acc[s][mt][2 * p];
        t[1] = (__bf16)acc[s][mt][2 * p + 1];
        pw[mt * 2 + p] = __builtin_bit_cast(int, t);
      }
    }
    // A-frag for GEMM2: lane needs Yr[m = cc][e = ks*32 + qd*8 + 2jw,+1].
    // Source word pw[2*(2ks + (qd>>1)) + (jw&1)] at lane ((2qd + (jw>>1))&3)*16+cc.
    // Two bpermutes (both mt_s candidates) + per-lane select on qd>>1.
    #pragma unroll
    for (int ks = 0; ks < 4; ++ks) {
      i32x4 aw;
      #pragma unroll
      for (int jw = 0; jw < 4; ++jw) {
        int srcl = ((((2 * qd + (jw >> 1)) & 3) * 16) + cc) * 4;
        int wlo = __builtin_amdgcn_ds_bpermute(srcl, pw[4 * ks + (jw & 1)]);
        int whi = __builtin_amdgcn_ds_bpermute(srcl, pw[4 * ks + 2 + (jw & 1)]);
        aw[jw] = (qd < 2) ? wlo : whi;
      }
      a2[s][ks] = __builtin_bit_cast(bf16x8, aw);
    }
  }

  // --- GEMM2: Z[m][e'] = sum_e Yr[m][e] * Q[e][e'] (reuse acc registers) ----
  #pragma unroll
  for (int s = 0; s < 2; ++s)
    #pragma unroll
    for (int nt = 0; nt < 8; ++nt) acc[s][nt] = (f32x4){0.f, 0.f, 0.f, 0.f};

  #pragma unroll
  for (int nt = 0; nt < 8; ++nt) {
    #pragma unroll
    for (int ks = 0; ks < 4; ++ks) {
      bf16x8 b2 = *(const bf16x8*)(wsQf + ((ks * 8 + nt) * 64 + lane) * 8);
      acc[0][nt] = __builtin_amdgcn_mfma_f32_16x16x32_bf16(a2[0][ks], b2, acc[0][nt], 0, 0, 0);
      acc[1][nt] = __builtin_amdgcn_mfma_f32_16x16x32_bf16(a2[1][ks], b2, acc[1][nt], 0, 0, 0);
    }
  }

  // --- epilogue: direct C-layout stores -------------------------------------
  // Per instr: rows qd*4+reg (4 rows) x cols nt*16+cc (16 contiguous f32 = 64B).
  #pragma unroll
  for (int s = 0; s < 2; ++s) {
    float* __restrict__ Ob = Og + (size_t)(r0 + s * 16) * kD;
    #pragma unroll
    for (int nt = 0; nt < 8; ++nt) {
      #pragma unroll
      for (int reg = 0; reg < 4; ++reg)
        Ob[(qd * 4 + reg) * kD + nt * 16 + cc] = acc[s][nt][reg];
    }
  }
}

extern "C" void kernel_launch(void* const* d_in, const int* in_sizes, int n_in,
                              void* d_out, int out_size, void* d_ws, size_t ws_size,
                              hipStream_t stream) {
  const float* q  = (const float*)d_in[0];
  const float* k  = (const float*)d_in[1];
  const float* vs = (const float*)d_in[2];
  __bf16* wsQrm = (__bf16*)d_ws;
  __bf16* wsQf  = wsQrm + kFragElems;

  rnrope_build_q<<<8, 1024, 0, stream>>>(vs, wsQrm, wsQf);
  rnrope_main<<<4096, 256, 0, stream>>>(q, k, wsQrm, wsQf, (float*)d_out);
}

// Round 2
// 492.631 us; speedup vs baseline: 1.0599x; 1.0599x over previous
//
#include <hip/hip_runtime.h>

typedef __bf16 bf16x8 __attribute__((ext_vector_type(8)));
typedef __bf16 bf16x4 __attribute__((ext_vector_type(4)));
typedef __bf16 bf16x2 __attribute__((ext_vector_type(2)));
typedef float  f32x4  __attribute__((ext_vector_type(4)));
typedef int    i32x4  __attribute__((ext_vector_type(4)));

static constexpr int kS = 8192;
static constexpr int kD = 128;
static constexpr int kRowsPerTensor = 2 * 16 * kS;            // 262144
static constexpr int kFragElems = kD * kD;                    // 16384 bf16 per matrix

// ---------------------------------------------------------------------------
// Kernel 1: build Householder product Q, column-parallel (one wave per column).
// Emits:
//   wsQA : Q in MFMA A-fragment order (A-operand of swapped GEMM1, staged to LDS)
//          table[((mt*4+ks)*64 + lane)*8 + j] = Q[mt*16 + (lane&15)][ks*32 + (lane>>4)*8 + j]
//   wsQf : Q in MFMA B-fragment order (B-operand of GEMM2, read from global)
// ---------------------------------------------------------------------------
__global__ __launch_bounds__(1024) void rnrope_build_q(
    const float* __restrict__ vs,
    __bf16* __restrict__ wsQA,
    __bf16* __restrict__ wsQf) {
  __shared__ float vsh[64 * 128];
  const int tid = threadIdx.x;
  for (int i = tid; i < 2048; i += 1024)
    ((float4*)vsh)[i] = ((const float4*)vs)[i];
  __syncthreads();

  const int col  = blockIdx.x * 16 + (tid >> 6);  // 0..127 (grid = 8 blocks)
  const int lane = tid & 63;

  float qlo = (col == lane)      ? 1.0f : 0.0f;   // Q[lane][col]
  float qhi = (col == lane + 64) ? 1.0f : 0.0f;   // Q[lane+64][col]

  for (int r = 0; r < 64; ++r) {
    float vlo = vsh[r * 128 + lane];
    float vhi = vsh[r * 128 + lane + 64];
    float t0 = vlo * qlo + vhi * qhi;   // partial v . q_col
    float t1 = vlo * vlo + vhi * vhi;   // partial v . v
    #pragma unroll
    for (int off = 32; off > 0; off >>= 1) {
      t0 += __shfl_xor(t0, off);
      t1 += __shfl_xor(t1, off);
    }
    float sf = 2.0f / (t1 + 1e-8f) * t0;
    qlo -= sf * vlo;
    qhi -= sf * vhi;
  }

  // A-frag(Q) table: element Q[i][col], i = lane, lane+64
  {
    const int ks = col >> 5, qdc = (col >> 3) & 3, jj = col & 7;
    #pragma unroll
    for (int h = 0; h < 2; ++h) {
      int i = lane + h * 64;
      float val = h ? qhi : qlo;
      int mt = i >> 4, rl = i & 15;
      wsQA[((mt * 4 + ks) * 64 + qdc * 16 + rl) * 8 + jj] = (__bf16)val;
    }
  }
  // B-frag(Q) table: element Q[i][col] at B[k=i][n=col]
  {
    const int nt = col >> 4;
    const int nn = col & 15;
    #pragma unroll
    for (int h = 0; h < 2; ++h) {
      int i = lane + h * 64;
      float val = h ? qhi : qlo;
      int ks = i >> 5, qdc = (i >> 3) & 3, jj = i & 7;
      wsQf[((ks * 8 + nt) * 64 + qdc * 16 + nn) * 8 + jj] = (__bf16)val;
    }
  }
}

// ---------------------------------------------------------------------------
// Kernel 2: one barrier per block. 512 threads, 128-row tile, 16 rows/wave.
//  - stage A-frag(Q) (32KB) + B-frag(X^T) (32KB, coalesced f32 loads + cvt)
//  - barrier
//  - GEMM1 swapped: Yt = Q * X^T   (both operands contiguous ds_read_b128)
//  - RoPE in-register (lane owns one row m=cc, e-pairs (mt, mt+4))
//  - pack -> ds_bpermute crossbar -> A-frag(Yrot)   (wave-private, no barrier)
//  - GEMM2: Z = Yrot * Q           (B-frags from global: wave-uniform 1KB loads)
//  - direct C-layout stores (4 x 64B segments per instr)
// ---------------------------------------------------------------------------
__global__ __launch_bounds__(512, 4) void rnrope_main(
    const float* __restrict__ qg, const float* __restrict__ kg,
    const __bf16* __restrict__ wsQA, const __bf16* __restrict__ wsQf,
    float* __restrict__ outg) {
  __shared__ __align__(16) __bf16 lds[2 * kFragElems];   // 64 KiB
  __bf16* ldsQ = lds;                 // 32 KiB: A-frag(Q)
  __bf16* ldsX = lds + kFragElems;    // 32 KiB: B-frag(X^T)

  const int tid    = threadIdx.x;
  const int blk    = blockIdx.x;          // 0..4095
  const int tensor = blk >> 11;           // 0 = q, 1 = k
  const int tile   = blk & 2047;
  const float* __restrict__ Xg = tensor ? kg : qg;
  float* __restrict__ Og = outg + (size_t)tensor * (size_t)kRowsPerTensor * kD;
  const int row0 = tile * 128;

  // stage Q A-frags (coalesced uint4 copy of the 32KB table)
  #pragma unroll
  for (int i = 0; i < 4; ++i)
    ((uint4*)ldsQ)[tid + i * 512] = ((const uint4*)wsQA)[tid + i * 512];

  // stage X tile, f32 -> bf16, swizzled into B-frag(X^T) order (coalesced loads)
  #pragma unroll
  for (int it = 0; it < 8; ++it) {
    int f    = tid + it * 512;            // float4 index, 4096 total
    int mloc = f >> 5;                    // row 0..127
    int q4   = f & 31;
    int k0   = q4 * 4;
    float4 x4 = ((const float4*)(Xg + (size_t)(row0 + mloc) * kD))[q4];
    int ks = k0 >> 5, qdc = (k0 >> 3) & 3, j = k0 & 7;
    int w = mloc >> 4, m = mloc & 15;
    int idx = ((w * 4 + ks) * 64 + qdc * 16 + m) * 8 + j;
    bf16x4 v;
    v[0] = (__bf16)x4.x; v[1] = (__bf16)x4.y; v[2] = (__bf16)x4.z; v[3] = (__bf16)x4.w;
    *(bf16x4*)(&ldsX[idx]) = v;
  }
  __syncthreads();

  const int w    = tid >> 6;     // wave 0..7, owns rows row0 + 16w .. +15
  const int lane = tid & 63;
  const int qd   = lane >> 4;
  const int cc   = lane & 15;

  // B-frags of X^T for this wave's 16 rows (contiguous 16B/lane)
  bf16x8 xb[4];
  #pragma unroll
  for (int ks = 0; ks < 4; ++ks)
    xb[ks] = *(const bf16x8*)(&ldsX[((w * 4 + ks) * 64 + lane) * 8]);

  // GEMM1 (swapped): Yt[e][m] = sum_d Q[e][d] * X[m][d]
  f32x4 acc[8];
  #pragma unroll
  for (int mt = 0; mt < 8; ++mt) acc[mt] = (f32x4){0.f, 0.f, 0.f, 0.f};
  #pragma unroll
  for (int mt = 0; mt < 8; ++mt) {
    #pragma unroll
    for (int ks = 0; ks < 4; ++ks) {
      bf16x8 a1 = *(const bf16x8*)(&ldsQ[((mt * 4 + ks) * 64 + lane) * 8]);
      acc[mt] = __builtin_amdgcn_mfma_f32_16x16x32_bf16(a1, xb[ks], acc[mt], 0, 0, 0);
    }
  }

  // RoPE in-register. C layout (swapped): lane holds Yt[e = mt*16+qd*4+reg][m = cc].
  // Pair (e, e+64) = (acc[mt], acc[mt+4]) same reg; lane's row is row0+w*16+cc.
  const float kNegL = -0.20762050593046967f;   // -log2(10000)/64
  {
    float spos = (float)((row0 + w * 16 + cc) & (kS - 1));
    #pragma unroll
    for (int mt = 0; mt < 4; ++mt) {
      #pragma unroll
      for (int reg = 0; reg < 4; ++reg) {
        float fe  = (float)(mt * 16 + qd * 4 + reg);
        float ang = spos * exp2f(kNegL * fe);
        float sv, cv;
        __sincosf(ang, &sv, &cv);
        float ylo = acc[mt][reg];
        float yhi = acc[mt + 4][reg];
        acc[mt][reg]     = ylo * cv - yhi * sv;   // e < 64
        acc[mt + 4][reg] = yhi * cv + ylo * sv;   // e >= 64
      }
    }
  }

  // pack pairs (reg 2p, 2p+1) -> dwords, then in-wave crossbar to A-frag(Yrot)
  int pw[16];
  #pragma unroll
  for (int mt = 0; mt < 8; ++mt) {
    #pragma unroll
    for (int p = 0; p < 2; ++p) {
      bf16x2 t;
      t[0] = (__bf16)acc[mt][2 * p];
      t[1] = (__bf16)acc[mt][2 * p + 1];
      pw[mt * 2 + p] = __builtin_bit_cast(int, t);
    }
  }
  bf16x8 a2[4];
  #pragma unroll
  for (int ks = 0; ks < 4; ++ks) {
    i32x4 aw;
    #pragma unroll
    for (int jw = 0; jw < 4; ++jw) {
      int srcl = ((((2 * qd + (jw >> 1)) & 3) * 16) + cc) * 4;
      int wlo = __builtin_amdgcn_ds_bpermute(srcl, pw[4 * ks + (jw & 1)]);
      int whi = __builtin_amdgcn_ds_bpermute(srcl, pw[4 * ks + 2 + (jw & 1)]);
      aw[jw] = (qd < 2) ? wlo : whi;
    }
    a2[ks] = __builtin_bit_cast(bf16x8, aw);
  }

  // GEMM2: Z[m][e'] = sum_e Yrot[m][e] * Q[e][e']  (B from global, wave-uniform)
  #pragma unroll
  for (int nt = 0; nt < 8; ++nt) acc[nt] = (f32x4){0.f, 0.f, 0.f, 0.f};
  #pragma unroll
  for (int nt = 0; nt < 8; ++nt) {
    #pragma unroll
    for (int ks = 0; ks < 4; ++ks) {
      bf16x8 b2 = *(const bf16x8*)(wsQf + ((ks * 8 + nt) * 64 + lane) * 8);
      acc[nt] = __builtin_amdgcn_mfma_f32_16x16x32_bf16(a2[ks], b2, acc[nt], 0, 0, 0);
    }
  }

  // direct C-layout stores: 4 rows x 64B contiguous per instruction
  float* __restrict__ Ob = Og + (size_t)(row0 + w * 16) * kD;
  #pragma unroll
  for (int nt = 0; nt < 8; ++nt) {
    #pragma unroll
    for (int reg = 0; reg < 4; ++reg)
      Ob[(qd * 4 + reg) * kD + nt * 16 + cc] = acc[nt][reg];
  }
}

extern "C" void kernel_launch(void* const* d_in, const int* in_sizes, int n_in,
                              void* d_out, int out_size, void* d_ws, size_t ws_size,
                              hipStream_t stream) {
  const float* q  = (const float*)d_in[0];
  const float* k  = (const float*)d_in[1];
  const float* vs = (const float*)d_in[2];
  __bf16* wsQA = (__bf16*)d_ws;
  __bf16* wsQf = wsQA + kFragElems;

  rnrope_build_q<<<8, 1024, 0, stream>>>(vs, wsQA, wsQf);
  rnrope_main<<<4096, 512, 0, stream>>>(q, k, wsQA, wsQf, (float*)d_out);
}